// Round 1
// baseline (635.764 us; speedup 1.0000x reference)
//
#include <hip/hip_runtime.h>
#include <math.h>

// UMGMQuantizer forward = two levels of (argmax over K of logit+gumbel) + codeword gather.
// Key insight: output depends ONLY on the argmax index per (n,m); softmax never matters.
// Screening with norm bounds prunes 2048 dots -> ~2-3 per (n,m); survivors re-scored in fp64.

namespace {
constexpr int Nn = 4096, Mm = 8, Kk = 2048, Dd = 128;
constexpr int MK = Mm * Kk;               // 16384 rows per codebook
constexpr double SQRTK = 45.254833995939045;  // sqrt(2048)
constexpr float MARGIN = 0.25f;           // covers v_log_f32 near-1 error + clip-bound diff

__device__ __forceinline__ double wsum_d(double v) {
#pragma unroll
  for (int o = 32; o > 0; o >>= 1) v += __shfl_xor(v, o);
  return v;
}
__device__ __forceinline__ float wsum_f(float v) {
#pragma unroll
  for (int o = 32; o > 0; o >>= 1) v += __shfl_xor(v, o);
  return v;
}
__device__ __forceinline__ float wmax_f(float v) {
#pragma unroll
  for (int o = 32; o > 0; o >>= 1) v = fmaxf(v, __shfl_xor(v, o));
  return v;
}

// Fast screening gumbel: 2x v_log_f32. Accuracy ~1e-6 except u near 1 (<= ~0.08 abs),
// which MARGIN absorbs.
__device__ __forceinline__ float fast_gumbel(float u) {
  float uc = fminf(fmaxf(u, 1e-6f), (float)(1.0 - 1e-6));
  float a = __log2f(uc);                 // log2(uc) < 0
  float t = -0.69314718f * a;            // -ln(uc) > 0
  return -0.69314718f * __log2f(t);      // -ln(-ln(uc))
}

// Exact gumbel in double (matches an fp64 numpy reference: clip in double, libm log).
__device__ __forceinline__ double gumbel_d(float u) {
  double uc = fmin(fmax((double)u, 1e-6), 1.0 - 1e-6);
  return -log(-log(uc));
}

__global__ __launch_bounds__(256) void c2_kernel(
    const float* __restrict__ cb0, const float* __restrict__ cb1,
    double* __restrict__ c2d0, double* __restrict__ c2d1,
    float* __restrict__ c2f0, float* __restrict__ c2f1,
    float* __restrict__ sf0, float* __restrict__ sf1) {
  int wid = threadIdx.x >> 6, lane = threadIdx.x & 63;
  int row = blockIdx.x * 4 + wid;        // 0..32767 (both codebooks)
  const float* cb = (row < MK) ? cb0 : cb1;
  int r = row & (MK - 1);
  float2 c = ((const float2*)(cb + (size_t)r * Dd))[lane];
  double s = (double)c.x * (double)c.x + (double)c.y * (double)c.y;
  s = wsum_d(s);
  if (lane == 0) {
    if (row < MK) { c2d0[r] = s; c2f0[r] = (float)s; sf0[r] = (float)sqrt(s); }
    else          { c2d1[r] = s; c2f1[r] = (float)s; sf1[r] = (float)sqrt(s); }
  }
}

// One wave per (n,m) pair. p is m-major so consecutive blocks share the c2/s tables (L1-hot).
template <bool L1>
__global__ __launch_bounds__(256) void level_kernel(
    const float* __restrict__ x,
    const float* __restrict__ cb,        // this level's codebook (m,K,D)
    const float* __restrict__ cb_prev,   // L1: codebook0 for residual
    const int* __restrict__ idx_prev,    // L1: level-0 indices
    const float* __restrict__ temp,      // (M,1)
    const float* __restrict__ u,         // this level's uniforms (N,M,K)
    const double* __restrict__ c2d,
    const float* __restrict__ c2f,
    const float* __restrict__ sf,
    int* __restrict__ idx_out,           // L0 writes
    float* __restrict__ out)             // L1 writes xHat
{
  const int wid = threadIdx.x >> 6, lane = threadIdx.x & 63;
  const int p = blockIdx.x * 4 + wid;    // 0..32767
  const int m = p >> 12;                 // p / 4096
  const int n = p & 4095;

  // z (residual for level 1); lane holds d = 2*lane, 2*lane+1
  float2 z = ((const float2*)(x + (size_t)n * 1024 + m * Dd))[lane];
  float2 dq0 = make_float2(0.f, 0.f);
  if (L1) {
    int i0 = idx_prev[p];
    dq0 = ((const float2*)(cb_prev + ((size_t)m * Kk + i0) * Dd))[lane];
    z.x -= dq0.x; z.y -= dq0.y;
  }
  float zn = sqrtf(wsum_f(z.x * z.x + z.y * z.y));
  double wd = (double)fmaxf(temp[m], 1e-6f) / SQRTK;  // T/sqrt(K), exact in double
  float wf = (float)wd;
  float tzn = 2.0f * zn;

  const float* urow = u + ((size_t)n * Mm + m) * Kk;
  const float4* u4 = (const float4*)urow;
  const float4* c24 = (const float4*)(c2f + m * Kk);
  const float4* s4 = (const float4*)(sf + m * Kk);

  // Pass 1: fast gumbel + score bounds; k = (j*64+lane)*4 + q
  float ub[32];
  float lbmax = -1e30f;
#pragma unroll
  for (int j = 0; j < 8; ++j) {
    float4 uu = u4[j * 64 + lane];
    float4 cc = c24[j * 64 + lane];
    float4 ss = s4[j * 64 + lane];
    float g0 = fast_gumbel(uu.x), g1 = fast_gumbel(uu.y);
    float g2 = fast_gumbel(uu.z), g3 = fast_gumbel(uu.w);
    float p0 = tzn * ss.x, p1 = tzn * ss.y, p2 = tzn * ss.z, p3 = tzn * ss.w;
    ub[j * 4 + 0] = g0 - (cc.x - p0) * wf;  lbmax = fmaxf(lbmax, g0 - (cc.x + p0) * wf);
    ub[j * 4 + 1] = g1 - (cc.y - p1) * wf;  lbmax = fmaxf(lbmax, g1 - (cc.y + p1) * wf);
    ub[j * 4 + 2] = g2 - (cc.z - p2) * wf;  lbmax = fmaxf(lbmax, g2 - (cc.z + p2) * wf);
    ub[j * 4 + 3] = g3 - (cc.w - p3) * wf;  lbmax = fmaxf(lbmax, g3 - (cc.w + p3) * wf);
  }
  float thr = wmax_f(lbmax) - MARGIN;

  // Pass 2: refine surviving candidates (~2-3 expected) in fp64.
  double bestS = -1e300;
  int bestK = 0;
  const double* c2row = c2d + m * Kk;
  const float* cbm = cb + (size_t)m * Kk * Dd;
#pragma unroll
  for (int j = 0; j < 8; ++j) {
#pragma unroll
    for (int q = 0; q < 4; ++q) {
      unsigned long long mask = __ballot(ub[j * 4 + q] >= thr);
      while (mask) {
        int l = (int)__ffsll(mask) - 1;
        mask &= mask - 1;
        int kc = j * 256 + l * 4 + q;
        float2 c = ((const float2*)(cbm + (size_t)kc * Dd))[lane];
        double dot = wsum_d((double)z.x * (double)c.x + (double)z.y * (double)c.y);
        // score (constant x2 term dropped; argmax-invariant)
        double sc = (2.0 * dot - c2row[kc]) * wd + gumbel_d(urow[kc]);
        if (sc > bestS) { bestS = sc; bestK = kc; }
      }
    }
  }

  if (L1) {
    float2 c1 = ((const float2*)(cbm + (size_t)bestK * Dd))[lane];
    ((float2*)(out + (size_t)n * 1024 + m * Dd))[lane] =
        make_float2(dq0.x + c1.x, dq0.y + c1.y);
  } else {
    if (lane == 0) idx_out[p] = bestK;
  }
}
}  // namespace

extern "C" void kernel_launch(void* const* d_in, const int* in_sizes, int n_in,
                              void* d_out, int out_size, void* d_ws, size_t ws_size,
                              hipStream_t stream) {
  const float* x   = (const float*)d_in[0];
  const float* cb0 = (const float*)d_in[1];
  const float* cb1 = (const float*)d_in[2];
  const float* t0  = (const float*)d_in[3];
  const float* t1  = (const float*)d_in[4];
  const float* u0  = (const float*)d_in[5];
  const float* u1  = (const float*)d_in[6];
  float* out = (float*)d_out;

  // workspace layout (655360 B total)
  char* ws = (char*)d_ws;
  double* c2d0 = (double*)ws;            // 16384 doubles
  double* c2d1 = c2d0 + MK;
  float* c2f0 = (float*)(c2d1 + MK);
  float* c2f1 = c2f0 + MK;
  float* sf0 = c2f1 + MK;
  float* sf1 = sf0 + MK;
  int* idx0 = (int*)(sf1 + MK);          // 32768 ints

  c2_kernel<<<8192, 256, 0, stream>>>(cb0, cb1, c2d0, c2d1, c2f0, c2f1, sf0, sf1);
  level_kernel<false><<<8192, 256, 0, stream>>>(x, cb0, nullptr, nullptr, t0, u0,
                                                c2d0, c2f0, sf0, idx0, nullptr);
  level_kernel<true><<<8192, 256, 0, stream>>>(x, cb1, cb0, idx0, t1, u1,
                                               c2d1, c2f1, sf1, nullptr, out);
}

// Round 2
// 623.333 us; speedup vs baseline: 1.0199x; 1.0199x over previous
//
#include <hip/hip_runtime.h>
#include <math.h>

// UMGMQuantizer forward = two chained argmax-over-K (logit+gumbel) + codeword gather.
// Softmax never affects the value; only argmax indices matter. Norm-bound screening
// prunes 2048 dots -> ~2-3 per (n,m); survivors re-scored exactly in fp64.
// Round 2: fused both levels into one kernel (elementwise dependency per (n,m)),
// de-bloated pass-2 (single while-body via 32-bit candidate mask), premultiplied tables.

namespace {
constexpr int Nn = 4096, Mm = 8, Kk = 2048, Dd = 128;
constexpr int MK = Mm * Kk;                    // 16384 rows per codebook
constexpr double SQRTK = 45.254833995939045;   // sqrt(2048)
constexpr float MARGIN = 0.25f;                // absorbs fast-gumbel err near u~1

__device__ __forceinline__ double wsum_d(double v) {
#pragma unroll
  for (int o = 32; o > 0; o >>= 1) v += __shfl_xor(v, o);
  return v;
}
__device__ __forceinline__ float wsum_f(float v) {
#pragma unroll
  for (int o = 32; o > 0; o >>= 1) v += __shfl_xor(v, o);
  return v;
}
__device__ __forceinline__ float wmax_f(float v) {
#pragma unroll
  for (int o = 32; o > 0; o >>= 1) v = fmaxf(v, __shfl_xor(v, o));
  return v;
}

// Screening gumbel: 2x v_log_f32; abs err <= ~0.08 only near u~1, covered by MARGIN.
__device__ __forceinline__ float fast_gumbel(float u) {
  float uc = fminf(fmaxf(u, 1e-6f), 0.999999f);
  float t = -0.69314718f * __log2f(uc);
  return -0.69314718f * __log2f(t);
}
// Exact gumbel in fp64 for final rescoring.
__device__ __forceinline__ double gumbel_d(float u) {
  double uc = fmin(fmax((double)u, 1e-6), 1.0 - 1e-6);
  return -log(-log(uc));
}

// Tables per (level, m, k): AS = {A = c2*w, S = 2*sqrt(c2)*w} (float2), c2d (double).
__global__ __launch_bounds__(256) void prep_kernel(
    const float* __restrict__ cb0, const float* __restrict__ cb1,
    const float* __restrict__ t0, const float* __restrict__ t1,
    float2* __restrict__ AS0, float2* __restrict__ AS1,
    double* __restrict__ c2d0, double* __restrict__ c2d1) {
  int wid = threadIdx.x >> 6, lane = threadIdx.x & 63;
  int row = blockIdx.x * 4 + wid;              // 0..32767 (both codebooks)
  int lvl = row >= MK;
  int r = row & (MK - 1);
  int m = r >> 11;
  const float* cb = lvl ? cb1 : cb0;
  const float* tp = lvl ? t1 : t0;
  float2 c = ((const float2*)(cb + (size_t)r * Dd))[lane];
  double s = (double)c.x * (double)c.x + (double)c.y * (double)c.y;
  s = wsum_d(s);
  if (lane == 0) {
    float wf = (float)((double)fmaxf(tp[m], 1e-6f) / SQRTK);
    float2 as;
    as.x = (float)s * wf;
    as.y = 2.0f * (float)sqrt(s) * wf;
    if (lvl) { c2d1[r] = s; AS1[r] = as; }
    else     { c2d0[r] = s; AS0[r] = as; }
  }
}

// One level's argmax for one (n,m), executed by a full wave.
__device__ __forceinline__ int argmax_level(
    float zx, float zy, int lane,
    const float* __restrict__ cbm,      // codebook + m*K*D
    const float* __restrict__ urow,     // u + (n*M+m)*K
    const float2* __restrict__ ASm,     // AS + m*K
    const double* __restrict__ c2m,     // c2d + m*K
    double wd) {
  float zn = sqrtf(wsum_f(zx * zx + zy * zy));
  const float4* u4 = (const float4*)urow;
  const float4* as4 = (const float4*)ASm;     // one float4 = {A,S,A,S} for 2 k's

  // Pass 1: score bounds for all K. k = (j*64+lane)*4 + q.
  float ub[32];
  float lbmax = -1e30f;
#pragma unroll
  for (int j = 0; j < 8; ++j) {
    float4 uu = u4[j * 64 + lane];
    float4 a0 = as4[(j * 64 + lane) * 2];      // k+0, k+1
    float4 a1 = as4[(j * 64 + lane) * 2 + 1];  // k+2, k+3
    float g0 = fast_gumbel(uu.x), g1 = fast_gumbel(uu.y);
    float g2 = fast_gumbel(uu.z), g3 = fast_gumbel(uu.w);
    float s0 = zn * a0.y, s1 = zn * a0.w, s2 = zn * a1.y, s3 = zn * a1.w;
    float b0 = g0 - a0.x, b1 = g1 - a0.z, b2 = g2 - a1.x, b3 = g3 - a1.z;
    ub[j * 4 + 0] = b0 + s0; lbmax = fmaxf(lbmax, b0 - s0);
    ub[j * 4 + 1] = b1 + s1; lbmax = fmaxf(lbmax, b1 - s1);
    ub[j * 4 + 2] = b2 + s2; lbmax = fmaxf(lbmax, b2 - s2);
    ub[j * 4 + 3] = b3 + s3; lbmax = fmaxf(lbmax, b3 - s3);
  }
  float thr = wmax_f(lbmax) - MARGIN;

  // Candidate bitmask per lane (static indexing keeps ub[] in VGPRs).
  unsigned mask32 = 0;
#pragma unroll
  for (int t = 0; t < 32; ++t) mask32 |= (ub[t] >= thr ? 1u : 0u) << t;

  // Pass 2: ONE copy of the heavy refine body; ~2-3 iterations per wave.
  double bestS = -1e300;
  int bestK = 0;
  while (true) {
    unsigned long long wm = __ballot(mask32 != 0);
    if (!wm) break;
    int l = (int)__ffsll(wm) - 1;
    unsigned lm = (unsigned)__shfl((int)mask32, l);
    int t = __builtin_ffs((int)lm) - 1;
    if (lane == l) mask32 &= mask32 - 1;
    int kc = ((t >> 2) << 8) + (l << 2) + (t & 3);
    float2 c = ((const float2*)(cbm + (size_t)kc * Dd))[lane];
    double dot = wsum_d((double)zx * (double)c.x + (double)zy * (double)c.y);
    double sc = (2.0 * dot - c2m[kc]) * wd + gumbel_d(urow[kc]);  // x2 term argmax-invariant
    if (sc > bestS) { bestS = sc; bestK = kc; }
  }
  return bestK;
}

__global__ __launch_bounds__(256, 4) void fused_kernel(
    const float* __restrict__ x,
    const float* __restrict__ cb0, const float* __restrict__ cb1,
    const float* __restrict__ t0, const float* __restrict__ t1,
    const float* __restrict__ u0, const float* __restrict__ u1,
    const float2* __restrict__ AS0, const float2* __restrict__ AS1,
    const double* __restrict__ c2d0, const double* __restrict__ c2d1,
    float* __restrict__ out) {
  const int wid = threadIdx.x >> 6, lane = threadIdx.x & 63;
  const int p = blockIdx.x * 4 + wid;   // 0..32767, m-major for L2 locality
  const int m = p >> 12;
  const int n = p & 4095;

  float2 z = ((const float2*)(x + (size_t)n * 1024 + m * Dd))[lane];
  double wd0 = (double)fmaxf(t0[m], 1e-6f) / SQRTK;
  double wd1 = (double)fmaxf(t1[m], 1e-6f) / SQRTK;

  const float* u0row = u0 + ((size_t)n * Mm + m) * Kk;
  const float* u1row = u1 + ((size_t)n * Mm + m) * Kk;
  const float* cb0m = cb0 + (size_t)m * Kk * Dd;
  const float* cb1m = cb1 + (size_t)m * Kk * Dd;

  // Level 0
  int b0 = argmax_level(z.x, z.y, lane, cb0m, u0row, AS0 + m * Kk, c2d0 + m * Kk, wd0);
  float2 c0 = ((const float2*)(cb0m + (size_t)b0 * Dd))[lane];

  // Level 1 on the residual
  float zx1 = z.x - c0.x, zy1 = z.y - c0.y;
  int b1 = argmax_level(zx1, zy1, lane, cb1m, u1row, AS1 + m * Kk, c2d1 + m * Kk, wd1);
  float2 c1 = ((const float2*)(cb1m + (size_t)b1 * Dd))[lane];

  ((float2*)(out + (size_t)n * 1024 + m * Dd))[lane] =
      make_float2(c0.x + c1.x, c0.y + c1.y);
}
}  // namespace

extern "C" void kernel_launch(void* const* d_in, const int* in_sizes, int n_in,
                              void* d_out, int out_size, void* d_ws, size_t ws_size,
                              hipStream_t stream) {
  const float* x   = (const float*)d_in[0];
  const float* cb0 = (const float*)d_in[1];
  const float* cb1 = (const float*)d_in[2];
  const float* t0  = (const float*)d_in[3];
  const float* t1  = (const float*)d_in[4];
  const float* u0  = (const float*)d_in[5];
  const float* u1  = (const float*)d_in[6];
  float* out = (float*)d_out;

  // ws: AS0/AS1 (16384 float2 each), c2d0/c2d1 (16384 double each) = 512 KB
  char* ws = (char*)d_ws;
  float2* AS0 = (float2*)ws;
  float2* AS1 = AS0 + MK;
  double* c2d0 = (double*)(AS1 + MK);
  double* c2d1 = c2d0 + MK;

  prep_kernel<<<8192, 256, 0, stream>>>(cb0, cb1, t0, t1, AS0, AS1, c2d0, c2d1);
  fused_kernel<<<8192, 256, 0, stream>>>(x, cb0, cb1, t0, t1, u0, u1,
                                         AS0, AS1, c2d0, c2d1, out);
}

// Round 3
// 569.422 us; speedup vs baseline: 1.1165x; 1.0947x over previous
//
#include <hip/hip_runtime.h>
#include <math.h>

// UMGMQuantizer forward = two chained argmax-over-K (logit+gumbel) + codeword gather.
// Round 3: log-free screening. gumbel(u) is monotone in u, so
//   gmax = gumbel(max_k u_k)  (pure fmaxf sweep, no logs)
//   candidate predicate g_k >= thr  <=>  u_k >= u_thr = exp(-exp(-thr))  (one fp64 calc/wave)
// with wave-uniform logit range bound R = w*(c2max - c2min + 4*zn*smax).
// Survivors (~2-3 per (n,m,level)) re-scored exactly in fp64. No per-k logs, no ub[32]
// spill array, no AS table stream.

namespace {
constexpr int Mm = 8, Kk = 2048, Dd = 128;
constexpr int MK = Mm * Kk;                    // 16384 rows per codebook
constexpr double SQRTK = 45.254833995939045;   // sqrt(2048)
constexpr double MARGIN = 0.05;                // fp64 thr math; covers float zn rounding

__device__ __forceinline__ double wsum_d(double v) {
#pragma unroll
  for (int o = 32; o > 0; o >>= 1) v += __shfl_xor(v, o);
  return v;
}
__device__ __forceinline__ float wsum_f(float v) {
#pragma unroll
  for (int o = 32; o > 0; o >>= 1) v += __shfl_xor(v, o);
  return v;
}
__device__ __forceinline__ float wmax_f(float v) {
#pragma unroll
  for (int o = 32; o > 0; o >>= 1) v = fmaxf(v, __shfl_xor(v, o));
  return v;
}

// Exact gumbel in fp64 (matches fp64 numpy semantics: clip, log).
__device__ __forceinline__ double gumbel_d(float u) {
  double uc = fmin(fmax((double)u, 1e-6), 1.0 - 1e-6);
  return -log(-log(uc));
}

// prep1: squared row norms of both codebooks (fp64). One wave per row.
__global__ __launch_bounds__(256) void prep1(
    const float* __restrict__ cb0, const float* __restrict__ cb1,
    double* __restrict__ c2d0, double* __restrict__ c2d1) {
  int wid = threadIdx.x >> 6, lane = threadIdx.x & 63;
  int row = blockIdx.x * 4 + wid;              // 0..32767
  int lvl = row >= MK;
  int r = row & (MK - 1);
  const float* cb = lvl ? cb1 : cb0;
  float2 c = ((const float2*)(cb + (size_t)r * Dd))[lane];
  double s = wsum_d((double)c.x * (double)c.x + (double)c.y * (double)c.y);
  if (lane == 0) { if (lvl) c2d1[r] = s; else c2d0[r] = s; }
}

// prep2: per (level,m): Rtab = {w*(c2max-c2min), 4*w*sqrt(c2max)} (conservative).
__global__ __launch_bounds__(256) void prep2(
    const double* __restrict__ c2d0, const double* __restrict__ c2d1,
    const float* __restrict__ t0, const float* __restrict__ t1,
    float2* __restrict__ Rtab) {
  int b = blockIdx.x;                          // 0..15
  int lvl = b >> 3, m = b & 7;
  const double* c2 = (lvl ? c2d1 : c2d0) + m * Kk;
  int tid = threadIdx.x;
  double mx = -1e300, mn = 1e300;
  for (int i = tid; i < Kk; i += 256) { double v = c2[i]; mx = fmax(mx, v); mn = fmin(mn, v); }
#pragma unroll
  for (int o = 32; o > 0; o >>= 1) {
    mx = fmax(mx, __shfl_xor(mx, o));
    mn = fmin(mn, __shfl_xor(mn, o));
  }
  __shared__ double smx[4], smn[4];
  int wid = tid >> 6, lane = tid & 63;
  if (lane == 0) { smx[wid] = mx; smn[wid] = mn; }
  __syncthreads();
  if (tid == 0) {
    mx = fmax(fmax(smx[0], smx[1]), fmax(smx[2], smx[3]));
    mn = fmin(fmin(smn[0], smn[1]), fmin(smn[2], smn[3]));
    double w = (double)fmaxf(lvl ? t1[m] : t0[m], 1e-6f) / SQRTK;
    float2 r;
    r.x = (float)(w * (mx - mn) * 1.0001);
    r.y = (float)(4.0 * w * sqrt(mx) * 1.0001);
    Rtab[b] = r;
  }
}

// One level's exact argmax for one (n,m), executed by a full wave.
__device__ __forceinline__ int do_level(
    float zx, float zy, int lane,
    const float* __restrict__ urow,    // u + (n*M+m)*K
    const float* __restrict__ cbm,     // codebook + m*K*D
    const double* __restrict__ c2m,    // c2d + m*K
    float2 rr, double wd) {
  const float4* u4 = (const float4*)urow;
  // Sweep: load u into registers (8 float4 = 32 VGPR), track max. No logs.
  float4 r[8];
  float um = 0.f;
#pragma unroll
  for (int j = 0; j < 8; ++j) {
    r[j] = u4[j * 64 + lane];
    um = fmaxf(um, fmaxf(fmaxf(r[j].x, r[j].y), fmaxf(r[j].z, r[j].w)));
  }
  um = wmax_f(um);
  float zn = sqrtf(wsum_f(zx * zx + zy * zy));
  // Wave-uniform threshold in exact fp64, inverted back to u-space.
  double thr = gumbel_d(um) - (double)(rr.x + rr.y * zn) - MARGIN;
  float uthr = (float)(exp(-exp(-thr)) * (1.0 - 1e-7));  // round down: conservative
  // Candidate bitmask straight from registers; bit t=j*4+q <-> k=(j*64+lane)*4+q
  unsigned mask32 = 0;
#pragma unroll
  for (int j = 0; j < 8; ++j) {
    mask32 |= (r[j].x >= uthr ? 1u : 0u) << (j * 4 + 0);
    mask32 |= (r[j].y >= uthr ? 1u : 0u) << (j * 4 + 1);
    mask32 |= (r[j].z >= uthr ? 1u : 0u) << (j * 4 + 2);
    mask32 |= (r[j].w >= uthr ? 1u : 0u) << (j * 4 + 3);
  }
  // Refine survivors (~2-3) exactly in fp64. Single shared loop body.
  double bestS = -1e300;
  int bestK = 0;
  while (true) {
    unsigned long long wm = __ballot(mask32 != 0);
    if (!wm) break;
    int l = (int)__ffsll(wm) - 1;
    unsigned lm = (unsigned)__shfl((int)mask32, l);
    int t = __builtin_ffs((int)lm) - 1;
    if (lane == l) mask32 &= mask32 - 1;
    int kc = ((t >> 2) << 8) + (l << 2) + (t & 3);
    float2 c = ((const float2*)(cbm + (size_t)kc * Dd))[lane];
    double dot = wsum_d((double)zx * (double)c.x + (double)zy * (double)c.y);
    double sc = (2.0 * dot - c2m[kc]) * wd + gumbel_d(urow[kc]);  // x2 const dropped
    if (sc > bestS || (sc == bestS && kc < bestK)) { bestS = sc; bestK = kc; }
  }
  return bestK;
}

__global__ __launch_bounds__(256) void fused_kernel(
    const float* __restrict__ x,
    const float* __restrict__ cb0, const float* __restrict__ cb1,
    const float* __restrict__ t0, const float* __restrict__ t1,
    const float* __restrict__ u0, const float* __restrict__ u1,
    const double* __restrict__ c2d0, const double* __restrict__ c2d1,
    const float2* __restrict__ Rtab,
    float* __restrict__ out) {
  const int wid = threadIdx.x >> 6, lane = threadIdx.x & 63;
  const int p = blockIdx.x * 4 + wid;   // 0..32767, m-major: c2d row stays L2-hot
  const int m = p >> 12;
  const int n = p & 4095;

  float2 z = ((const float2*)(x + (size_t)n * 1024 + m * Dd))[lane];
  double wd0 = (double)fmaxf(t0[m], 1e-6f) / SQRTK;
  double wd1 = (double)fmaxf(t1[m], 1e-6f) / SQRTK;

  const float* u0row = u0 + ((size_t)n * Mm + m) * Kk;
  const float* u1row = u1 + ((size_t)n * Mm + m) * Kk;
  const float* cb0m = cb0 + (size_t)m * Kk * Dd;
  const float* cb1m = cb1 + (size_t)m * Kk * Dd;

  int b0 = do_level(z.x, z.y, lane, u0row, cb0m, c2d0 + m * Kk, Rtab[m], wd0);
  float2 c0 = ((const float2*)(cb0m + (size_t)b0 * Dd))[lane];

  int b1 = do_level(z.x - c0.x, z.y - c0.y, lane, u1row, cb1m, c2d1 + m * Kk,
                    Rtab[8 + m], wd1);
  float2 c1 = ((const float2*)(cb1m + (size_t)b1 * Dd))[lane];

  ((float2*)(out + (size_t)n * 1024 + m * Dd))[lane] =
      make_float2(c0.x + c1.x, c0.y + c1.y);
}
}  // namespace

extern "C" void kernel_launch(void* const* d_in, const int* in_sizes, int n_in,
                              void* d_out, int out_size, void* d_ws, size_t ws_size,
                              hipStream_t stream) {
  const float* x   = (const float*)d_in[0];
  const float* cb0 = (const float*)d_in[1];
  const float* cb1 = (const float*)d_in[2];
  const float* t0  = (const float*)d_in[3];
  const float* t1  = (const float*)d_in[4];
  const float* u0  = (const float*)d_in[5];
  const float* u1  = (const float*)d_in[6];
  float* out = (float*)d_out;

  // ws: c2d0/c2d1 (16384 doubles each) + Rtab (16 float2) = 256 KB + 128 B
  char* ws = (char*)d_ws;
  double* c2d0 = (double*)ws;
  double* c2d1 = c2d0 + MK;
  float2* Rtab = (float2*)(c2d1 + MK);

  prep1<<<8192, 256, 0, stream>>>(cb0, cb1, c2d0, c2d1);
  prep2<<<16, 256, 0, stream>>>(c2d0, c2d1, t0, t1, Rtab);
  fused_kernel<<<8192, 256, 0, stream>>>(x, cb0, cb1, t0, t1, u0, u1,
                                         c2d0, c2d1, Rtab, out);
}